// Round 1
// baseline (407.785 us; speedup 1.0000x reference)
//
#include <hip/hip_runtime.h>
#include <math.h>

#define EPS_F 1e-8f

__global__ __launch_bounds__(256) void rot_iou3d_loss(
    const float* __restrict__ pred,
    const float* __restrict__ target,
    const float* __restrict__ weight,
    float* __restrict__ out,
    int n, float inv_n)
{
    int i = blockIdx.x * blockDim.x + threadIdx.x;
    float contrib = 0.0f;
    if (i < n) {
        const float* p = pred + (size_t)i * 7;
        const float* q = target + (size_t)i * 7;
        float p0=p[0],p1=p[1],p2=p[2],p3=p[3],p4=p[4],p5=p[5],p6=p[6];
        float q0=q[0],q1=q[1],q2=q[2],q3=q[3],q4=q[4],q5=q[5],q6=q[6];

        const float tx[4] = {0.5f,-0.5f,-0.5f,0.5f};
        const float ty[4] = {0.5f, 0.5f,-0.5f,-0.5f};
        float c1x[4], c1y[4], c2x[4], c2y[4];
        {
            float ca = cosf(p6), sa = sinf(p6);
            #pragma unroll
            for (int k=0;k<4;k++){
                float x4 = tx[k]*p3, y4 = ty[k]*p4;
                c1x[k] = x4*ca - y4*sa + p0;
                c1y[k] = x4*sa + y4*ca + p1;
            }
            float cb = cosf(q6), sb = sinf(q6);
            #pragma unroll
            for (int k=0;k<4;k++){
                float x4 = tx[k]*q3, y4 = ty[k]*q4;
                c2x[k] = x4*cb - y4*sb + q0;
                c2y[k] = x4*sb + y4*cb + q1;
            }
        }

        // 24 candidate vertices: 0-3 = c1 corners, 4-7 = c2 corners, 8-23 = edge intersections
        float vx[24], vy[24];
        bool  vm[24];

        // box_in_box: c1 corners inside c2  (a=corner0, b=corner1, d=corner3)
        {
            float ax=c2x[0], ay=c2y[0];
            float abx=c2x[1]-ax, aby=c2y[1]-ay;
            float adx=c2x[3]-ax, ady=c2y[3]-ay;
            float dab = abx*abx + aby*aby;
            float dad = adx*adx + ady*ady;
            const float e = 1e-6f;
            #pragma unroll
            for (int k=0;k<4;k++){
                float amx=c1x[k]-ax, amy=c1y[k]-ay;
                float pab = (amx*abx + amy*aby) / dab;
                float pad = (amx*adx + amy*ady) / dad;
                vm[k] = (pab > -e) && (pab < 1.0f+e) && (pad > -e) && (pad < 1.0f+e);
                vx[k] = c1x[k]; vy[k] = c1y[k];
            }
        }
        // c2 corners inside c1
        {
            float ax=c1x[0], ay=c1y[0];
            float abx=c1x[1]-ax, aby=c1y[1]-ay;
            float adx=c1x[3]-ax, ady=c1y[3]-ay;
            float dab = abx*abx + aby*aby;
            float dad = adx*adx + ady*ady;
            const float e = 1e-6f;
            #pragma unroll
            for (int k=0;k<4;k++){
                float amx=c2x[k]-ax, amy=c2y[k]-ay;
                float pab = (amx*abx + amy*aby) / dab;
                float pad = (amx*adx + amy*ady) / dad;
                vm[4+k] = (pab > -e) && (pab < 1.0f+e) && (pad > -e) && (pad < 1.0f+e);
                vx[4+k] = c2x[k]; vy[4+k] = c2y[k];
            }
        }
        // edge-edge intersections (i over c1 edges, j over c2 edges)
        #pragma unroll
        for (int ii=0; ii<4; ii++){
            float p1x=c1x[ii], p1y=c1y[ii];
            float p2x=c1x[(ii+1)&3], p2y=c1y[(ii+1)&3];
            float d1x=p2x-p1x, d1y=p2y-p1y;
            #pragma unroll
            for (int jj=0; jj<4; jj++){
                float p3x=c2x[jj], p3y=c2y[jj];
                float p4x=c2x[(jj+1)&3], p4y=c2y[(jj+1)&3];
                float d2x=p4x-p3x, d2y=p4y-p3y;
                float qpx=p3x-p1x, qpy=p3y-p1y;
                float denom = d1x*d2y - d1y*d2x;
                float dn = denom + EPS_F;
                float t = (qpx*d2y - qpy*d2x) / dn;
                float u = (qpx*d1y - qpy*d1x) / dn;
                bool m = (t > 0.0f) && (t < 1.0f) && (u > 0.0f) && (u < 1.0f);
                int idx = 8 + ii*4 + jj;
                vm[idx] = m;
                vx[idx] = m ? (p1x + t*d1x) : 0.0f;
                vy[idx] = m ? (p1y + t*d1y) : 0.0f;
            }
        }

        // centroid of valid vertices
        float sx=0.0f, sy=0.0f; int cnt=0;
        #pragma unroll
        for (int k=0;k<24;k++){
            if (vm[k]) { sx += vx[k]; sy += vy[k]; cnt++; }
        }
        int num = cnt > 1 ? cnt : 1;
        float mx = sx / (float)num, my = sy / (float)num;

        // compact valid points + angle
        float px[24], py[24], pa[24];
        int K = 0;
        #pragma unroll
        for (int k=0;k<24;k++){
            if (vm[k]) {
                px[K] = vx[k]; py[K] = vy[k];
                pa[K] = atan2f(vy[k]-my, vx[k]-mx);
                K++;
            }
        }

        // stable insertion sort by angle (matches jnp.argsort stability)
        for (int a=1; a<K; a++){
            float kx=px[a], ky=py[a], kang=pa[a];
            int b=a-1;
            while (b>=0 && pa[b] > kang){
                px[b+1]=px[b]; py[b+1]=py[b]; pa[b+1]=pa[b];
                b--;
            }
            px[b+1]=kx; py[b+1]=ky; pa[b+1]=kang;
        }

        // shoelace over the sorted valid polygon (invalid slots collapse to v0 in ref = no-op)
        float area = 0.0f;
        for (int k=0; k<K; k++){
            int k2 = (k+1==K) ? 0 : k+1;
            area += px[k]*py[k2] - py[k]*px[k2];
        }
        float inter2d = 0.5f * fabsf(area);

        float zmax = fminf(p2 + 0.5f*p5, q2 + 0.5f*q5);
        float zmin = fmaxf(p2 - 0.5f*p5, q2 - 0.5f*q5);
        float inter3d = inter2d * fmaxf(zmax - zmin, 0.0f);
        float v1 = p3*p4*p5, v2 = q3*q4*q5;
        float uni = v1 + v2 - inter3d;
        float iou = inter3d / (uni + EPS_F);
        contrib = (1.0f - iou) * weight[i] * inv_n;
    }

    // block reduction: wave shuffle then LDS
    #pragma unroll
    for (int off=32; off>0; off>>=1)
        contrib += __shfl_down(contrib, off, 64);

    __shared__ float wsum[4];
    int lane = threadIdx.x & 63;
    int wid  = threadIdx.x >> 6;
    if (lane == 0) wsum[wid] = contrib;
    __syncthreads();
    if (threadIdx.x == 0) {
        float s = wsum[0] + wsum[1] + wsum[2] + wsum[3];
        atomicAdd(out, s);
    }
}

extern "C" void kernel_launch(void* const* d_in, const int* in_sizes, int n_in,
                              void* d_out, int out_size, void* d_ws, size_t ws_size,
                              hipStream_t stream) {
    const float* pred   = (const float*)d_in[0];
    const float* target = (const float*)d_in[1];
    const float* weight = (const float*)d_in[2];
    float* out = (float*)d_out;
    int n = in_sizes[0] / 7;

    hipMemsetAsync(out, 0, sizeof(float), stream);

    const int block = 256;
    const int grid = (n + block - 1) / block;
    rot_iou3d_loss<<<grid, block, 0, stream>>>(pred, target, weight, out, n, 1.0f / (float)n);
}

// Round 2
// 173.732 us; speedup vs baseline: 2.3472x; 2.3472x over previous
//
#include <hip/hip_runtime.h>
#include <math.h>

#define EPS_F 1e-8f

__device__ __forceinline__ float frcp(float x) { return __builtin_amdgcn_rcpf(x); }

// Monotone pseudo-angle in [0,4): same ordering as atan2 up to a cyclic
// rotation (start at +x axis instead of -pi). Shoelace over a cyclic order is
// rotation-invariant, so this is exact up to fp noise.
__device__ __forceinline__ float pang(float dx, float dy) {
    float r = dx * frcp(fabsf(dx) + fabsf(dy) + 1e-30f);
    return (dy >= 0.0f) ? (1.0f - r) : (3.0f + r);
}

__global__ __launch_bounds__(256) void rot_iou3d_loss(
    const float* __restrict__ pred,
    const float* __restrict__ target,
    const float* __restrict__ weight,
    float* __restrict__ out,
    int n, float inv_n)
{
    int i = blockIdx.x * blockDim.x + threadIdx.x;
    float contrib = 0.0f;
    if (i < n) {
        const float* p = pred + (size_t)i * 7;
        const float* q = target + (size_t)i * 7;
        float p0=p[0],p1=p[1],p2=p[2],p3=p[3],p4=p[4],p5=p[5],p6=p[6];
        float q0=q[0],q1=q[1],q2=q[2],q3=q[3],q4=q[4],q5=q[5],q6=q[6];

        const float tx[4] = {0.5f,-0.5f,-0.5f,0.5f};
        const float ty[4] = {0.5f, 0.5f,-0.5f,-0.5f};
        float c1x[4], c1y[4], c2x[4], c2y[4];
        {
            float sa, ca, sb, cb;
            __sincosf(p6, &sa, &ca);
            __sincosf(q6, &sb, &cb);
            #pragma unroll
            for (int k=0;k<4;k++){
                float x4 = tx[k]*p3, y4 = ty[k]*p4;
                c1x[k] = x4*ca - y4*sa + p0;
                c1y[k] = x4*sa + y4*ca + p1;
                float x5 = tx[k]*q3, y5 = ty[k]*q4;
                c2x[k] = x5*cb - y5*sb + q0;
                c2y[k] = x5*sb + y5*cb + q1;
            }
        }

        // 24 candidates: 0-3 c1 corners, 4-7 c2 corners, 8-23 edge intersections
        float PX[32], PY[32], ANG[32];
        bool  M[24];

        // c1 corners inside c2
        {
            float ax=c2x[0], ay=c2y[0];
            float abx=c2x[1]-ax, aby=c2y[1]-ay;
            float adx=c2x[3]-ax, ady=c2y[3]-ay;
            float rab = frcp(abx*abx + aby*aby);
            float rad = frcp(adx*adx + ady*ady);
            const float e = 1e-6f;
            #pragma unroll
            for (int k=0;k<4;k++){
                float amx=c1x[k]-ax, amy=c1y[k]-ay;
                float pab = (amx*abx + amy*aby) * rab;
                float pad = (amx*adx + amy*ady) * rad;
                M[k] = (pab > -e) && (pab < 1.0f+e) && (pad > -e) && (pad < 1.0f+e);
                PX[k] = c1x[k]; PY[k] = c1y[k];
            }
        }
        // c2 corners inside c1
        {
            float ax=c1x[0], ay=c1y[0];
            float abx=c1x[1]-ax, aby=c1y[1]-ay;
            float adx=c1x[3]-ax, ady=c1y[3]-ay;
            float rab = frcp(abx*abx + aby*aby);
            float rad = frcp(adx*adx + ady*ady);
            const float e = 1e-6f;
            #pragma unroll
            for (int k=0;k<4;k++){
                float amx=c2x[k]-ax, amy=c2y[k]-ay;
                float pab = (amx*abx + amy*aby) * rab;
                float pad = (amx*adx + amy*ady) * rad;
                M[4+k] = (pab > -e) && (pab < 1.0f+e) && (pad > -e) && (pad < 1.0f+e);
                PX[4+k] = c2x[k]; PY[4+k] = c2y[k];
            }
        }
        // edge-edge intersections
        #pragma unroll
        for (int ii=0; ii<4; ii++){
            float p1x=c1x[ii], p1y=c1y[ii];
            float d1x=c1x[(ii+1)&3]-p1x, d1y=c1y[(ii+1)&3]-p1y;
            #pragma unroll
            for (int jj=0; jj<4; jj++){
                float p3x=c2x[jj], p3y=c2y[jj];
                float d2x=c2x[(jj+1)&3]-p3x, d2y=c2y[(jj+1)&3]-p3y;
                float qpx=p3x-p1x, qpy=p3y-p1y;
                float rdn = frcp(d1x*d2y - d1y*d2x + EPS_F);
                float t = (qpx*d2y - qpy*d2x) * rdn;
                float u = (qpx*d1y - qpy*d1x) * rdn;
                bool m = (t > 0.0f) && (t < 1.0f) && (u > 0.0f) && (u < 1.0f);
                int idx = 8 + ii*4 + jj;
                M[idx]  = m;
                PX[idx] = p1x + t*d1x;
                PY[idx] = p1y + t*d1y;
            }
        }

        // centroid over valid
        float sx=0.0f, sy=0.0f; int cnt=0;
        #pragma unroll
        for (int k=0;k<24;k++){
            if (M[k]) { sx += PX[k]; sy += PY[k]; cnt++; }
        }
        float rnum = frcp((float)(cnt > 1 ? cnt : 1));
        float mx = sx * rnum, my = sy * rnum;

        // pseudo-angles; invalid & padding -> 1e9
        #pragma unroll
        for (int k=0;k<24;k++)
            ANG[k] = M[k] ? pang(PX[k]-mx, PY[k]-my) : 1e9f;
        #pragma unroll
        for (int k=24;k<32;k++){ ANG[k] = 1e9f; PX[k] = 0.0f; PY[k] = 0.0f; }

        // 32-wide bitonic sort by ANG (branchless, all-static indices)
        #pragma unroll
        for (int k = 2; k <= 32; k <<= 1) {
            #pragma unroll
            for (int j = k >> 1; j > 0; j >>= 1) {
                #pragma unroll
                for (int t = 0; t < 32; ++t) {
                    int l = t ^ j;
                    if (l > t) {
                        bool up = ((t & k) == 0);
                        bool sw = up ? (ANG[t] > ANG[l]) : (ANG[t] < ANG[l]);
                        float ta=ANG[t], txx=PX[t], tyy=PY[t];
                        float la=ANG[l], lxx=PX[l], lyy=PY[l];
                        ANG[t] = sw ? la : ta;  ANG[l] = sw ? ta : la;
                        PX[t]  = sw ? lxx : txx; PX[l] = sw ? txx : lxx;
                        PY[t]  = sw ? lyy : tyy; PY[l] = sw ? tyy : lyy;
                    }
                }
            }
        }

        // invalid slots collapse to sorted v0 (exactly the reference semantics)
        float x0 = PX[0], y0 = PY[0];
        #pragma unroll
        for (int k=0;k<32;k++){
            bool inv = ANG[k] > 100.0f;
            PX[k] = inv ? x0 : PX[k];
            PY[k] = inv ? y0 : PY[k];
        }

        // shoelace with wraparound (padding contributes 0)
        float area = 0.0f;
        #pragma unroll
        for (int k=0;k<32;k++){
            int k2 = (k+1) & 31;
            area += PX[k]*PY[k2] - PY[k]*PX[k2];
        }
        float inter2d = 0.5f * fabsf(area);

        float zmax = fminf(p2 + 0.5f*p5, q2 + 0.5f*q5);
        float zmin = fmaxf(p2 - 0.5f*p5, q2 - 0.5f*q5);
        float inter3d = inter2d * fmaxf(zmax - zmin, 0.0f);
        float v1 = p3*p4*p5, v2 = q3*q4*q5;
        float iou = inter3d * frcp(v1 + v2 - inter3d + EPS_F);
        contrib = (1.0f - iou) * weight[i] * inv_n;
    }

    // block reduction: wave shuffle then LDS
    #pragma unroll
    for (int off=32; off>0; off>>=1)
        contrib += __shfl_down(contrib, off, 64);

    __shared__ float wsum[4];
    int lane = threadIdx.x & 63;
    int wid  = threadIdx.x >> 6;
    if (lane == 0) wsum[wid] = contrib;
    __syncthreads();
    if (threadIdx.x == 0) {
        float s = wsum[0] + wsum[1] + wsum[2] + wsum[3];
        atomicAdd(out, s);
    }
}

extern "C" void kernel_launch(void* const* d_in, const int* in_sizes, int n_in,
                              void* d_out, int out_size, void* d_ws, size_t ws_size,
                              hipStream_t stream) {
    const float* pred   = (const float*)d_in[0];
    const float* target = (const float*)d_in[1];
    const float* weight = (const float*)d_in[2];
    float* out = (float*)d_out;
    int n = in_sizes[0] / 7;

    hipMemsetAsync(out, 0, sizeof(float), stream);

    const int block = 256;
    const int grid = (n + block - 1) / block;
    rot_iou3d_loss<<<grid, block, 0, stream>>>(pred, target, weight, out, n, 1.0f / (float)n);
}

// Round 3
// 134.941 us; speedup vs baseline: 3.0219x; 1.2875x over previous
//
#include <hip/hip_runtime.h>
#include <math.h>

#define EPS_F 1e-8f

__device__ __forceinline__ float frcp(float x) { return __builtin_amdgcn_rcpf(x); }

// Clip directed segment (world: P->Q, local-to-other-rect: pl->ql) against the
// axis-aligned rect [-hw,hw]x[-hh,hh] (Liang-Barsky slab test, branchless).
// Return cross(A,B) of the clipped world-space endpoints, or 0 if no overlap.
// Summing this over all 8 directed rectangle edges (both rects CCW) gives the
// shoelace sum of the convex intersection polygon, order-free.
__device__ __forceinline__ float clip_contrib(
    float Px, float Py, float Qx, float Qy,
    float plx, float ply, float qlx, float qly,
    float hw, float hh)
{
    float dlx = qlx - plx, dly = qly - ply;
    float ix = frcp(dlx), iy = frcp(dly);
    float tax = (-hw - plx) * ix, tbx = (hw - plx) * ix;
    float tay = (-hh - ply) * iy, tby = (hh - ply) * iy;
    float t0 = fmaxf(fmaxf(fminf(tax, tbx), fminf(tay, tby)), 0.0f);
    float t1 = fminf(fminf(fmaxf(tax, tbx), fmaxf(tay, tby)), 1.0f);
    bool valid = t0 < t1;
    float dwx = Qx - Px, dwy = Qy - Py;
    float Ax = Px + t0 * dwx, Ay = Py + t0 * dwy;
    float Bx = Px + t1 * dwx, By = Py + t1 * dwy;
    float c = Ax * By - Ay * Bx;
    return valid ? c : 0.0f;
}

__global__ __launch_bounds__(256) void rot_iou3d_loss(
    const float* __restrict__ pred,
    const float* __restrict__ target,
    const float* __restrict__ weight,
    float* __restrict__ out,
    int n, float inv_n)
{
    int i = blockIdx.x * blockDim.x + threadIdx.x;
    float contrib = 0.0f;
    if (i < n) {
        const float* p = pred + (size_t)i * 7;
        const float* q = target + (size_t)i * 7;
        float p0=p[0],p1=p[1],p2=p[2],p3=p[3],p4=p[4],p5=p[5],p6=p[6];
        float q0=q[0],q1=q[1],q2=q[2],q3=q[3],q4=q[4],q5=q[5],q6=q[6];

        float sa, ca, sb, cb;
        __sincosf(p6, &sa, &ca);
        __sincosf(q6, &sb, &cb);

        // Common frame: world translated so box1 center is the origin
        // (translation-invariant shoelace, better fp conditioning).
        float cxx = q0 - p0, cyy = q1 - p1;   // box2 center in this frame

        const float tx[4] = {0.5f,-0.5f,-0.5f,0.5f};
        const float ty[4] = {0.5f, 0.5f,-0.5f,-0.5f};  // CCW order

        float w1x[4], w1y[4], w2x[4], w2y[4];   // corners, common frame
        float l1x[4], l1y[4], l2x[4], l2y[4];   // corners in the OTHER box's local frame
        #pragma unroll
        for (int k = 0; k < 4; k++) {
            float x4 = tx[k]*p3, y4 = ty[k]*p4;
            w1x[k] = x4*ca - y4*sa;
            w1y[k] = x4*sa + y4*ca;
            float x5 = tx[k]*q3, y5 = ty[k]*q4;
            w2x[k] = x5*cb - y5*sb + cxx;
            w2y[k] = x5*sb + y5*cb + cyy;
            // box1 corner -> box2 local frame (R2^T * (w1 - c2))
            float dx = w1x[k] - cxx, dy = w1y[k] - cyy;
            l1x[k] =  dx*cb + dy*sb;
            l1y[k] = -dx*sb + dy*cb;
            // box2 corner -> box1 local frame (box1 center at origin)
            l2x[k] =  w2x[k]*ca + w2y[k]*sa;
            l2y[k] = -w2x[k]*sa + w2y[k]*ca;
        }

        float hw1 = 0.5f*p3, hh1 = 0.5f*p4;
        float hw2 = 0.5f*q3, hh2 = 0.5f*q4;

        float s = 0.0f;
        #pragma unroll
        for (int k = 0; k < 4; k++) {
            int k2 = (k+1) & 3;
            // edges of box1 clipped by box2
            s += clip_contrib(w1x[k],w1y[k], w1x[k2],w1y[k2],
                              l1x[k],l1y[k], l1x[k2],l1y[k2], hw2, hh2);
            // edges of box2 clipped by box1
            s += clip_contrib(w2x[k],w2y[k], w2x[k2],w2y[k2],
                              l2x[k],l2y[k], l2x[k2],l2y[k2], hw1, hh1);
        }
        float inter2d = 0.5f * fabsf(s);

        float zmax = fminf(p2 + 0.5f*p5, q2 + 0.5f*q5);
        float zmin = fmaxf(p2 - 0.5f*p5, q2 - 0.5f*q5);
        float inter3d = inter2d * fmaxf(zmax - zmin, 0.0f);
        float v1 = p3*p4*p5, v2 = q3*q4*q5;
        float iou = inter3d * frcp(v1 + v2 - inter3d + EPS_F);
        contrib = (1.0f - iou) * weight[i] * inv_n;
    }

    // block reduction: wave shuffle then LDS
    #pragma unroll
    for (int off = 32; off > 0; off >>= 1)
        contrib += __shfl_down(contrib, off, 64);

    __shared__ float wsum[4];
    int lane = threadIdx.x & 63;
    int wid  = threadIdx.x >> 6;
    if (lane == 0) wsum[wid] = contrib;
    __syncthreads();
    if (threadIdx.x == 0) {
        float ssum = wsum[0] + wsum[1] + wsum[2] + wsum[3];
        atomicAdd(out, ssum);
    }
}

extern "C" void kernel_launch(void* const* d_in, const int* in_sizes, int n_in,
                              void* d_out, int out_size, void* d_ws, size_t ws_size,
                              hipStream_t stream) {
    const float* pred   = (const float*)d_in[0];
    const float* target = (const float*)d_in[1];
    const float* weight = (const float*)d_in[2];
    float* out = (float*)d_out;
    int n = in_sizes[0] / 7;

    hipMemsetAsync(out, 0, sizeof(float), stream);

    const int block = 256;
    const int grid = (n + block - 1) / block;
    rot_iou3d_loss<<<grid, block, 0, stream>>>(pred, target, weight, out, n, 1.0f / (float)n);
}

// Round 6
// 103.165 us; speedup vs baseline: 3.9527x; 1.3080x over previous
//
#include <hip/hip_runtime.h>
#include <math.h>

#define EPS_F 1e-8f

__device__ __forceinline__ float frcp(float x) { return __builtin_amdgcn_rcpf(x); }

// Clip directed segment (world: P->Q, local-to-other-rect: pl->ql) against the
// axis-aligned rect [-hw,hw]x[-hh,hh] (Liang-Barsky slab test, branchless).
// Return cross(A,B) of the clipped world-space endpoints, or 0 if no overlap.
// Summing over all 8 directed rectangle edges (both rects CCW) gives the
// shoelace sum of the convex intersection polygon, order-free.
__device__ __forceinline__ float clip_contrib(
    float Px, float Py, float Qx, float Qy,
    float plx, float ply, float qlx, float qly,
    float hw, float hh)
{
    float dlx = qlx - plx, dly = qly - ply;
    float ix = frcp(dlx), iy = frcp(dly);
    float tax = (-hw - plx) * ix, tbx = (hw - plx) * ix;
    float tay = (-hh - ply) * iy, tby = (hh - ply) * iy;
    float t0 = fmaxf(fmaxf(fminf(tax, tbx), fminf(tay, tby)), 0.0f);
    float t1 = fminf(fminf(fmaxf(tax, tbx), fmaxf(tay, tby)), 1.0f);
    bool valid = t0 < t1;
    float dwx = Qx - Px, dwy = Qy - Py;
    float Ax = Px + t0 * dwx, Ay = Py + t0 * dwy;
    float Bx = Px + t1 * dwx, By = Py + t1 * dwy;
    float c = Ax * By - Ay * Bx;
    return valid ? c : 0.0f;
}

// Full per-box loss term (already weighted and scaled by 1/n).
__device__ __forceinline__ float box_loss(
    const float* __restrict__ pred,
    const float* __restrict__ target,
    const float* __restrict__ weight,
    int i, float inv_n)
{
    const float* p = pred + (size_t)i * 7;
    const float* q = target + (size_t)i * 7;
    float p0=p[0],p1=p[1],p2=p[2],p3=p[3],p4=p[4],p5=p[5],p6=p[6];
    float q0=q[0],q1=q[1],q2=q[2],q3=q[3],q4=q[4],q5=q[5],q6=q[6];
    float w = weight[i];

    float sa, ca, sb, cb;
    __sincosf(p6, &sa, &ca);
    __sincosf(q6, &sb, &cb);

    // Common frame: box1 center at origin.
    float cxx = q0 - p0, cyy = q1 - p1;

    const float tx[4] = {0.5f,-0.5f,-0.5f,0.5f};
    const float ty[4] = {0.5f, 0.5f,-0.5f,-0.5f};  // CCW

    float w1x[4], w1y[4], w2x[4], w2y[4];
    float l1x[4], l1y[4], l2x[4], l2y[4];
    #pragma unroll
    for (int k = 0; k < 4; k++) {
        float x4 = tx[k]*p3, y4 = ty[k]*p4;
        w1x[k] = x4*ca - y4*sa;
        w1y[k] = x4*sa + y4*ca;
        float x5 = tx[k]*q3, y5 = ty[k]*q4;
        w2x[k] = x5*cb - y5*sb + cxx;
        w2y[k] = x5*sb + y5*cb + cyy;
        float dx = w1x[k] - cxx, dy = w1y[k] - cyy;
        l1x[k] =  dx*cb + dy*sb;
        l1y[k] = -dx*sb + dy*cb;
        l2x[k] =  w2x[k]*ca + w2y[k]*sa;
        l2y[k] = -w2x[k]*sa + w2y[k]*ca;
    }

    float hw1 = 0.5f*p3, hh1 = 0.5f*p4;
    float hw2 = 0.5f*q3, hh2 = 0.5f*q4;

    float s = 0.0f;
    #pragma unroll
    for (int k = 0; k < 4; k++) {
        int k2 = (k+1) & 3;
        s += clip_contrib(w1x[k],w1y[k], w1x[k2],w1y[k2],
                          l1x[k],l1y[k], l1x[k2],l1y[k2], hw2, hh2);
        s += clip_contrib(w2x[k],w2y[k], w2x[k2],w2y[k2],
                          l2x[k],l2y[k], l2x[k2],l2y[k2], hw1, hh1);
    }
    float inter2d = 0.5f * fabsf(s);

    float zmax = fminf(p2 + 0.5f*p5, q2 + 0.5f*q5);
    float zmin = fmaxf(p2 - 0.5f*p5, q2 - 0.5f*q5);
    float inter3d = inter2d * fmaxf(zmax - zmin, 0.0f);
    float v1 = p3*p4*p5, v2 = q3*q4*q5;
    float iou = inter3d * frcp(v1 + v2 - inter3d + EPS_F);
    return (1.0f - iou) * w * inv_n;
}

__global__ __launch_bounds__(512) void rot_iou3d_loss(
    const float* __restrict__ pred,
    const float* __restrict__ target,
    const float* __restrict__ weight,
    float* __restrict__ out,
    int n, float inv_n)
{
    int t = blockIdx.x * blockDim.x + threadIdx.x;
    int i0 = 2*t, i1 = 2*t + 1;

    // Two independent chains per thread -> 2x ILP against load + VALU latency.
    float c0 = (i0 < n) ? box_loss(pred, target, weight, i0, inv_n) : 0.0f;
    float c1 = (i1 < n) ? box_loss(pred, target, weight, i1, inv_n) : 0.0f;
    float contrib = c0 + c1;

    // wave shuffle reduce, then LDS across the 8 waves
    #pragma unroll
    for (int off = 32; off > 0; off >>= 1)
        contrib += __shfl_down(contrib, off, 64);

    __shared__ float wsum[8];
    int lane = threadIdx.x & 63;
    int wid  = threadIdx.x >> 6;
    if (lane == 0) wsum[wid] = contrib;
    __syncthreads();
    if (threadIdx.x == 0) {
        float ssum = 0.0f;
        #pragma unroll
        for (int k = 0; k < 8; k++) ssum += wsum[k];
        atomicAdd(out, ssum);
    }
}

extern "C" void kernel_launch(void* const* d_in, const int* in_sizes, int n_in,
                              void* d_out, int out_size, void* d_ws, size_t ws_size,
                              hipStream_t stream) {
    const float* pred   = (const float*)d_in[0];
    const float* target = (const float*)d_in[1];
    const float* weight = (const float*)d_in[2];
    float* out = (float*)d_out;
    int n = in_sizes[0] / 7;

    hipMemsetAsync(out, 0, sizeof(float), stream);

    const int block = 512;
    int threads_needed = (n + 1) / 2;
    int grid = (threads_needed + block - 1) / block;
    rot_iou3d_loss<<<grid, block, 0, stream>>>(pred, target, weight, out, n, 1.0f / (float)n);
}

// Round 8
// 103.011 us; speedup vs baseline: 3.9587x; 1.0015x over previous
//
#include <hip/hip_runtime.h>
#include <math.h>

#define EPS_F 1e-8f

__device__ __forceinline__ float frcp(float x) { return __builtin_amdgcn_rcpf(x); }

// Clip directed segment (world: P->Q, local-to-other-rect: pl->ql) against the
// axis-aligned rect [-hw,hw]x[-hh,hh] (Liang-Barsky slab test, branchless).
// Return cross(A,B) of the clipped world-space endpoints, or 0 if no overlap.
// Summing over all 8 directed rectangle edges (both rects CCW) gives the
// shoelace sum of the convex intersection polygon, order-free.
__device__ __forceinline__ float clip_contrib(
    float Px, float Py, float Qx, float Qy,
    float plx, float ply, float qlx, float qly,
    float hw, float hh)
{
    float dlx = qlx - plx, dly = qly - ply;
    float ix = frcp(dlx), iy = frcp(dly);
    float tax = (-hw - plx) * ix, tbx = (hw - plx) * ix;
    float tay = (-hh - ply) * iy, tby = (hh - ply) * iy;
    float t0 = fmaxf(fmaxf(fminf(tax, tbx), fminf(tay, tby)), 0.0f);
    float t1 = fminf(fminf(fmaxf(tax, tbx), fmaxf(tay, tby)), 1.0f);
    bool valid = t0 < t1;
    float dwx = Qx - Px, dwy = Qy - Py;
    float Ax = Px + t0 * dwx, Ay = Py + t0 * dwy;
    float Bx = Px + t1 * dwx, By = Py + t1 * dwy;
    float c = Ax * By - Ay * Bx;
    return valid ? c : 0.0f;
}

// Per-box loss term from register values (already weighted, scaled by 1/n).
__device__ __forceinline__ float box_loss_v(
    float p0, float p1, float p2, float p3, float p4, float p5, float p6,
    float q0, float q1, float q2, float q3, float q4, float q5, float q6,
    float w, float inv_n)
{
    float sa, ca, sb, cb;
    __sincosf(p6, &sa, &ca);
    __sincosf(q6, &sb, &cb);

    // Common frame: box1 center at origin.
    float cxx = q0 - p0, cyy = q1 - p1;

    const float tx[4] = {0.5f,-0.5f,-0.5f,0.5f};
    const float ty[4] = {0.5f, 0.5f,-0.5f,-0.5f};  // CCW

    float w1x[4], w1y[4], w2x[4], w2y[4];
    float l1x[4], l1y[4], l2x[4], l2y[4];
    #pragma unroll
    for (int k = 0; k < 4; k++) {
        float x4 = tx[k]*p3, y4 = ty[k]*p4;
        w1x[k] = x4*ca - y4*sa;
        w1y[k] = x4*sa + y4*ca;
        float x5 = tx[k]*q3, y5 = ty[k]*q4;
        w2x[k] = x5*cb - y5*sb + cxx;
        w2y[k] = x5*sb + y5*cb + cyy;
        float dx = w1x[k] - cxx, dy = w1y[k] - cyy;
        l1x[k] =  dx*cb + dy*sb;
        l1y[k] = -dx*sb + dy*cb;
        l2x[k] =  w2x[k]*ca + w2y[k]*sa;
        l2y[k] = -w2x[k]*sa + w2y[k]*ca;
    }

    float hw1 = 0.5f*p3, hh1 = 0.5f*p4;
    float hw2 = 0.5f*q3, hh2 = 0.5f*q4;

    float s = 0.0f;
    #pragma unroll
    for (int k = 0; k < 4; k++) {
        int k2 = (k+1) & 3;
        s += clip_contrib(w1x[k],w1y[k], w1x[k2],w1y[k2],
                          l1x[k],l1y[k], l1x[k2],l1y[k2], hw2, hh2);
        s += clip_contrib(w2x[k],w2y[k], w2x[k2],w2y[k2],
                          l2x[k],l2y[k], l2x[k2],l2y[k2], hw1, hh1);
    }
    float inter2d = 0.5f * fabsf(s);

    float zmax = fminf(p2 + 0.5f*p5, q2 + 0.5f*q5);
    float zmin = fmaxf(p2 - 0.5f*p5, q2 - 0.5f*q5);
    float inter3d = inter2d * fmaxf(zmax - zmin, 0.0f);
    float v1 = p3*p4*p5, v2 = q3*q4*q5;
    float iou = inter3d * frcp(v1 + v2 - inter3d + EPS_F);
    return (1.0f - iou) * w * inv_n;
}

__device__ __forceinline__ float box_loss_gather(
    const float* __restrict__ pred, const float* __restrict__ target,
    const float* __restrict__ weight, int i, float inv_n)
{
    const float* p = pred + (size_t)i * 7;
    const float* q = target + (size_t)i * 7;
    return box_loss_v(p[0],p[1],p[2],p[3],p[4],p[5],p[6],
                      q[0],q[1],q[2],q[3],q[4],q[5],q[6],
                      weight[i], inv_n);
}

__global__ __launch_bounds__(512) void rot_iou3d_loss(
    const float* __restrict__ pred,
    const float* __restrict__ target,
    const float* __restrict__ weight,
    float* __restrict__ out,
    int n, float inv_n)
{
    int t = blockIdx.x * blockDim.x + threadIdx.x;
    int i0 = 4 * t;
    float contrib = 0.0f;

    if (i0 + 3 < n) {
        // 4 boxes = 28 floats = exactly 7 aligned float4 loads per tensor.
        const float4* P4 = (const float4*)(pred   + (size_t)i0 * 7);
        const float4* Q4 = (const float4*)(target + (size_t)i0 * 7);
        float4 W4 = *(const float4*)(weight + i0);

        float pv[28], qv[28];
        #pragma unroll
        for (int j = 0; j < 7; j++) {
            float4 a = P4[j];
            pv[4*j+0] = a.x; pv[4*j+1] = a.y; pv[4*j+2] = a.z; pv[4*j+3] = a.w;
            float4 b = Q4[j];
            qv[4*j+0] = b.x; qv[4*j+1] = b.y; qv[4*j+2] = b.z; qv[4*j+3] = b.w;
        }
        float wv[4] = {W4.x, W4.y, W4.z, W4.w};

        // 4 independent chains; all indices compile-time after unroll.
        #pragma unroll
        for (int k = 0; k < 4; k++) {
            const float* p = pv + 7*k;
            const float* q = qv + 7*k;
            contrib += box_loss_v(p[0],p[1],p[2],p[3],p[4],p[5],p[6],
                                  q[0],q[1],q[2],q[3],q[4],q[5],q[6],
                                  wv[k], inv_n);
        }
    } else {
        #pragma unroll
        for (int k = 0; k < 4; k++) {
            int i = i0 + k;
            if (i < n) contrib += box_loss_gather(pred, target, weight, i, inv_n);
        }
    }

    // wave shuffle reduce, then LDS across the 8 waves
    #pragma unroll
    for (int off = 32; off > 0; off >>= 1)
        contrib += __shfl_down(contrib, off, 64);

    __shared__ float wsum[8];
    int lane = threadIdx.x & 63;
    int wid  = threadIdx.x >> 6;
    if (lane == 0) wsum[wid] = contrib;
    __syncthreads();
    if (threadIdx.x == 0) {
        float ssum = 0.0f;
        #pragma unroll
        for (int k = 0; k < 8; k++) ssum += wsum[k];
        atomicAdd(out, ssum);
    }
}

extern "C" void kernel_launch(void* const* d_in, const int* in_sizes, int n_in,
                              void* d_out, int out_size, void* d_ws, size_t ws_size,
                              hipStream_t stream) {
    const float* pred   = (const float*)d_in[0];
    const float* target = (const float*)d_in[1];
    const float* weight = (const float*)d_in[2];
    float* out = (float*)d_out;
    int n = in_sizes[0] / 7;

    hipMemsetAsync(out, 0, sizeof(float), stream);

    const int block = 512;
    int threads_needed = (n + 3) / 4;
    int grid = (threads_needed + block - 1) / block;
    rot_iou3d_loss<<<grid, block, 0, stream>>>(pred, target, weight, out, n, 1.0f / (float)n);
}